// Round 6
// baseline (2820.681 us; speedup 1.0000x reference)
//
#include <hip/hip_runtime.h>
#include <math.h>

// Problem constants (from reference): B=1024, C=256, H=W=24
static constexpr int B_N  = 1024;
static constexpr int C_N  = 256;
static constexpr int HW_N = 576;           // floats per channel = 144 float4
static constexpr float TEMP_INV = 1.0f / 0.07f;

static constexpr int TEXT_BLOCKS = 32;
static constexpr int POOL_BLOCKS = 16384;  // 16 channels each (4 waves x 4 ch)
static constexpr int GEMM_BLOCKS = 256;    // 16x16 tiles of 64x64

typedef __attribute__((ext_vector_type(8))) short bf16x8;
typedef __attribute__((ext_vector_type(4))) float f32x4;
typedef __attribute__((ext_vector_type(4))) float f4v;

// Control block in ws (zeroed by hipMemsetAsync each call)
struct Ctrl {
    float    loss_acc;     // +0
    unsigned ticket;       // +4
    unsigned text_cnt;     // +8   target 32
    unsigned grp_cnt[16];  // +12  target 1024 each (64 images x 16 blocks)
};

// float -> bf16 round-to-nearest-even (inputs finite)
static __device__ __forceinline__ unsigned short f2bf(float f) {
    unsigned u = __float_as_uint(f);
    return (unsigned short)((u + 0x7FFFu + ((u >> 16) & 1u)) >> 16);
}
static __device__ __forceinline__ float bf2f(unsigned short h) {
    return __uint_as_float(((unsigned)h) << 16);
}

// ---------------------------------------------------------------------------
// One fused kernel, producer-consumer:
//  Blocks [0,32)            : text rows -> normalized bf16 Bb; publish text_cnt.
//  Blocks [32, 32+16384)    : pooling (4 channels/wave, 9 deep NT loads,
//                             interleaved butterflies) -> unnormalized bf16
//                             means in Ab; publish grp_cnt[image_group].
//  Blocks [16416, 16672)    : GEMM consumers. Spin (s_sleep) on their image
//                             group + text counters, then MFMA straight from
//                             L2-resident Ab/Bb (NO LDS staging -> pool
//                             occupancy unaffected), deferred normalization
//                             from the in-register A fragments, fused BCE
//                             loss + ticket finalize. Tile 0 is ready ~6%
//                             into the pool, so 15/16 of GEMM work overlaps.
// Deadlock-free: <=256 consumer blocks can never exhaust the wave slots the
// (LDS-free) producer blocks need, so producers always make progress.
// ---------------------------------------------------------------------------
__global__ __launch_bounds__(256) void fused_kernel(const float* __restrict__ img,
                                                    const float* __restrict__ text,
                                                    unsigned short* __restrict__ Ab,
                                                    unsigned short* __restrict__ Bb,
                                                    const int* __restrict__ labels,
                                                    Ctrl* __restrict__ ctrl,
                                                    float* __restrict__ out) {
    __shared__ float invA[64];
    __shared__ float red[4];

    const unsigned bid = blockIdx.x;
    const int t    = threadIdx.x;
    const int w    = t >> 6;
    const int lane = t & 63;

    if (bid < TEXT_BLOCKS) {
        // ---------------- text: fp32 L2-normalize + bf16 cast -> Bb --------
        const int r0 = bid * 32 + w * 8;
        #pragma unroll
        for (int rr = 0; rr < 8; ++rr) {
            const int r = r0 + rr;
            const f4v v = ((const f4v*)(text + (size_t)r * C_N))[lane];
            float ss = v.x * v.x + v.y * v.y + v.z * v.z + v.w * v.w;
            #pragma unroll
            for (int off = 32; off > 0; off >>= 1) ss += __shfl_xor(ss, off, 64);
            const float inv = 1.0f / fmaxf(sqrtf(ss), 1e-12f);   // matches F.normalize
            ushort4 o;
            o.x = f2bf(v.x * inv); o.y = f2bf(v.y * inv);
            o.z = f2bf(v.z * inv); o.w = f2bf(v.w * inv);
            ((ushort4*)(Bb + (size_t)r * C_N))[lane] = o;
        }
        __threadfence();                 // release our stores (device scope)
        __syncthreads();                 // all threads fenced
        if (t == 0) atomicAdd(&ctrl->text_cnt, 1u);
        return;
    }

    if (bid < TEXT_BLOCKS + POOL_BLOCKS) {
        // ---------------- pool: 4 channels per wave ------------------------
        const int g = bid - TEXT_BLOCKS;               // 0..16383
        const size_t ch4 = (size_t)g * 16 + (size_t)w * 4;
        const f4v* src = (const f4v*)img + ch4 * 144;

        f4v vv[9];
        #pragma unroll
        for (int j = 0; j < 9; ++j)
            vv[j] = __builtin_nontemporal_load(&src[j * 64 + lane]);

        float a0 = 0.f, a1 = 0.f, a2 = 0.f, a3 = 0.f;
        #pragma unroll
        for (int j = 0; j < 9; ++j) {
            const int idx = j * 64 + lane;             // f4 index in [0, 576)
            const float s = (vv[j].x + vv[j].y) + (vv[j].z + vv[j].w);
            a0 += (idx < 144)               ? s : 0.0f;
            a1 += (idx >= 144 && idx < 288) ? s : 0.0f;
            a2 += (idx >= 288 && idx < 432) ? s : 0.0f;
            a3 += (idx >= 432)              ? s : 0.0f;
        }
        #pragma unroll
        for (int off = 32; off > 0; off >>= 1) {
            a0 += __shfl_xor(a0, off, 64);
            a1 += __shfl_xor(a1, off, 64);
            a2 += __shfl_xor(a2, off, 64);
            a3 += __shfl_xor(a3, off, 64);
        }
        if (lane == 0) {
            const float sc = 1.0f / (float)HW_N;
            ushort4 o;
            o.x = f2bf(a0 * sc); o.y = f2bf(a1 * sc);
            o.z = f2bf(a2 * sc); o.w = f2bf(a3 * sc);
            ((ushort4*)Ab)[ch4 >> 2] = o;              // unnormalized means
        }
        __threadfence();
        __syncthreads();
        if (t == 0) atomicAdd(&ctrl->grp_cnt[g >> 10], 1u);  // image group = (g/16)/64
        return;
    }

    // ---------------- GEMM consumer ----------------------------------------
    const int gid = bid - (TEXT_BLOCKS + POOL_BLOCKS);  // 0..255
    const int rowBase = (gid & 15) << 6;
    const int colBase = (gid >> 4) << 6;

    if (t == 0) {
        const unsigned* gc = &ctrl->grp_cnt[gid & 15];
        while (__hip_atomic_load(gc, __ATOMIC_ACQUIRE, __HIP_MEMORY_SCOPE_AGENT) < 1024u)
            __builtin_amdgcn_s_sleep(16);
        while (__hip_atomic_load(&ctrl->text_cnt, __ATOMIC_ACQUIRE, __HIP_MEMORY_SCOPE_AGENT) < 32u)
            __builtin_amdgcn_s_sleep(2);
    }
    __syncthreads();
    __threadfence();                     // acquire: invalidate before reading Ab/Bb

    const int m16 = lane & 15;
    const int kg  = lane >> 4;

    // A fragments straight from L2-resident Ab: row = rowBase + w*16 + m16,
    // k-chunk kc = s*4+kg (16B each). 32 VGPRs, reused for norm + MFMA.
    const unsigned short* arow = Ab + (size_t)(rowBase + (w << 4) + m16) * C_N;
    bf16x8 aF[8];
    #pragma unroll
    for (int s = 0; s < 8; ++s)
        aF[s] = *(const bf16x8*)(arow + (((s << 2) + kg) << 3));

    // Deferred normalization: this lane holds the kg-quarter of its row.
    {
        float ss = 0.0f;
        #pragma unroll
        for (int s = 0; s < 8; ++s) {
            #pragma unroll
            for (int e = 0; e < 8; ++e) {
                const float f = bf2f((unsigned short)aF[s][e]);
                ss += f * f;
            }
        }
        ss += __shfl_xor(ss, 16, 64);    // combine the 4 quarters (kg bits)
        ss += __shfl_xor(ss, 32, 64);
        if (kg == 0) invA[(w << 4) + m16] = 1.0f / fmaxf(sqrtf(ss), 1e-12f);
    }
    __syncthreads();

    // MFMA: B fragments streamed from L2-resident Bb (normalized text rows).
    const unsigned short* bbase = Bb + (size_t)colBase * C_N;
    f32x4 acc[4] = {{0.f, 0.f, 0.f, 0.f}, {0.f, 0.f, 0.f, 0.f},
                    {0.f, 0.f, 0.f, 0.f}, {0.f, 0.f, 0.f, 0.f}};
    #pragma unroll
    for (int s = 0; s < 8; ++s) {
        const int koff = ((s << 2) + kg) << 3;          // element offset in row
        #pragma unroll
        for (int ct = 0; ct < 4; ++ct) {
            const bf16x8 b = *(const bf16x8*)(bbase + (size_t)((ct << 4) + m16) * C_N + koff);
            acc[ct] = __builtin_amdgcn_mfma_f32_16x16x32_bf16(aF[s], b, acc[ct], 0, 0, 0);
        }
    }

    // Epilogue: logits -> BCE terms -> block reduction -> ticket finalize.
    // D frag: col = lane&15, row = (lane>>4)*4 + reg  [measured m89/m91]
    float lsum = 0.0f;
    const int lr0 = (w << 4) + (kg << 2);
    float sA[4]; int labi[4];
    #pragma unroll
    for (int r = 0; r < 4; ++r) {
        sA[r]   = invA[lr0 + r] * TEMP_INV;
        labi[r] = labels[rowBase + lr0 + r];
    }
    #pragma unroll
    for (int ct = 0; ct < 4; ++ct) {
        const int gj = colBase + (ct << 4) + m16;
        const int labj = labels[gj];
        #pragma unroll
        for (int r = 0; r < 4; ++r) {
            const float x = acc[ct][r] * sA[r];
            const float z = (labi[r] == labj) ? 1.0f : 0.0f;
            const float sp = fmaxf(x, 0.0f) + __logf(1.0f + __expf(-fabsf(x)));
            lsum += sp - x * z;
        }
    }
    #pragma unroll
    for (int off = 32; off > 0; off >>= 1) lsum += __shfl_xor(lsum, off, 64);
    if ((t & 63) == 0) red[w] = lsum;
    __syncthreads();
    if (t == 0) {
        const float bsum = red[0] + red[1] + red[2] + red[3];
        atomicAdd(&ctrl->loss_acc, bsum);
        __threadfence();
        const unsigned old = atomicAdd(&ctrl->ticket, 1u);
        if (old == GEMM_BLOCKS - 1) {    // last of 256 consumer blocks
            const float total = atomicAdd(&ctrl->loss_acc, 0.0f);  // device-scope read
            out[0] = total * (1.0f / ((float)B_N * (float)B_N));
        }
    }
}

extern "C" void kernel_launch(void* const* d_in, const int* in_sizes, int n_in,
                              void* d_out, int out_size, void* d_ws, size_t ws_size,
                              hipStream_t stream) {
    const float* img    = (const float*)d_in[0];   // [1024,256,24,24] fp32
    const float* text   = (const float*)d_in[1];   // [1024,256] fp32
    const int*   labels = (const int*)d_in[2];     // [1024] int32 (JAX demotes int64)
    float* out = (float*)d_out;

    char* ws = (char*)d_ws;
    unsigned short* Ab   = (unsigned short*)ws;                 // 512 KiB bf16 (unnormalized means)
    unsigned short* Bb   = (unsigned short*)(ws + (512 << 10)); // 512 KiB bf16 (normalized text)
    Ctrl*           ctrl = (Ctrl*)(ws + (1 << 20));             // 76 B control block

    // Zero flags/accumulator every call (capture-legal; makes the spin logic
    // correct on every graph replay, including the first post-poison one).
    hipMemsetAsync(ctrl, 0, 256, stream);

    fused_kernel<<<TEXT_BLOCKS + POOL_BLOCKS + GEMM_BLOCKS, 256, 0, stream>>>(
        img, text, Ab, Bb, labels, ctrl, out);
}

// Round 7
// 132.012 us; speedup vs baseline: 21.3668x; 21.3668x over previous
//
#include <hip/hip_runtime.h>
#include <math.h>

// Problem constants (from reference): B=1024, C=256, H=W=24
static constexpr int B_N  = 1024;
static constexpr int C_N  = 256;
static constexpr int HW_N = 576;           // floats per channel = 144 float4
static constexpr float TEMP_INV = 1.0f / 0.07f;

static constexpr int GEMM_BLOCKS = 1024;   // 32x32 tiles of the 1024x1024 logits

typedef __attribute__((ext_vector_type(8))) short bf16x8;
typedef __attribute__((ext_vector_type(4))) float f32x4;
typedef __attribute__((ext_vector_type(4))) float f4v;

// Control block in ws. part[i*16] (64B-strided, no false sharing) hold loss
// partials; ticket elects the finalizing block. Zeroed by pool block 0 (runs
// one launch earlier -> safe on every graph replay).
struct Ctrl {
    float    part[16 * 16];
    unsigned ticket;
};

// float -> bf16 round-to-nearest-even (inputs finite)
static __device__ __forceinline__ unsigned short f2bf(float f) {
    unsigned u = __float_as_uint(f);
    return (unsigned short)((u + 0x7FFFu + ((u >> 16) & 1u)) >> 16);
}
static __device__ __forceinline__ float bf2f(unsigned short h) {
    return __uint_as_float(((unsigned)h) << 16);
}

// ---------------------------------------------------------------------------
// Kernel A: pool + concurrent text normalize.
//  Blocks 0..31    : text rows (32/block): fp32 L2-normalize + bf16 -> Bb.
//                    Block 0 threads 0..16 zero the Ctrl partials + ticket.
//  Blocks 32..16415: pooling. Each wave owns 4 channels = 576 float4.
//                    9 dense loads/lane issued before any use (deep vmcnt
//                    pipe), select-accumulate into 4 channel partials,
//                    4 interleaved butterflies, lane 0 writes the 4
//                    UNNORMALIZED means as bf16 to Ab (normalization is
//                    deferred to the GEMM, which recomputes row norms).
// ---------------------------------------------------------------------------
__global__ __launch_bounds__(256) void pool_kernel(const float* __restrict__ img,
                                                   const float* __restrict__ text,
                                                   unsigned short* __restrict__ Ab,
                                                   unsigned short* __restrict__ Bb,
                                                   Ctrl* __restrict__ ctrl) {
    const int t    = threadIdx.x;
    const int w    = t >> 6;
    const int lane = t & 63;

    if (blockIdx.x < 32) {
        if (blockIdx.x == 0 && t < 17) {
            if (t < 16) ctrl->part[t * 16] = 0.0f;
            else        ctrl->ticket = 0u;
        }
        const int r0 = blockIdx.x * 32 + w * 8;
        #pragma unroll
        for (int rr = 0; rr < 8; ++rr) {
            const int r = r0 + rr;
            const f4v v = ((const f4v*)(text + (size_t)r * C_N))[lane];
            float ss = v.x * v.x + v.y * v.y + v.z * v.z + v.w * v.w;
            #pragma unroll
            for (int off = 32; off > 0; off >>= 1) ss += __shfl_xor(ss, off, 64);
            const float inv = 1.0f / fmaxf(sqrtf(ss), 1e-12f);   // matches F.normalize
            ushort4 o;
            o.x = f2bf(v.x * inv); o.y = f2bf(v.y * inv);
            o.z = f2bf(v.z * inv); o.w = f2bf(v.w * inv);
            ((ushort4*)(Bb + (size_t)r * C_N))[lane] = o;
        }
        return;
    }

    const int g = blockIdx.x - 32;                 // 0..16383, 16 channels each
    const size_t ch4 = (size_t)g * 16 + (size_t)w * 4;
    const f4v* src = (const f4v*)img + ch4 * 144;

    // Issue all 9 loads before any use (independent dests -> deep vmcnt pipe).
    f4v vv[9];
    #pragma unroll
    for (int j = 0; j < 9; ++j)
        vv[j] = src[j * 64 + lane];

    float a0 = 0.f, a1 = 0.f, a2 = 0.f, a3 = 0.f;
    #pragma unroll
    for (int j = 0; j < 9; ++j) {
        const int idx = j * 64 + lane;             // f4 index in [0, 576)
        const float s = (vv[j].x + vv[j].y) + (vv[j].z + vv[j].w);
        // channel boundaries at 144/288/432; 6 of 9 j's fold at compile time
        a0 += (idx < 144)               ? s : 0.0f;
        a1 += (idx >= 144 && idx < 288) ? s : 0.0f;
        a2 += (idx >= 288 && idx < 432) ? s : 0.0f;
        a3 += (idx >= 432)              ? s : 0.0f;
    }

    // 4 interleaved butterflies: independent chains hide bpermute latency.
    #pragma unroll
    for (int off = 32; off > 0; off >>= 1) {
        a0 += __shfl_xor(a0, off, 64);
        a1 += __shfl_xor(a1, off, 64);
        a2 += __shfl_xor(a2, off, 64);
        a3 += __shfl_xor(a3, off, 64);
    }
    if (lane == 0) {
        const float sc = 1.0f / (float)HW_N;
        ushort4 o;
        o.x = f2bf(a0 * sc); o.y = f2bf(a1 * sc);
        o.z = f2bf(a2 * sc); o.w = f2bf(a3 * sc);
        ((ushort4*)Ab)[ch4 >> 2] = o;              // unnormalized means
    }
}

// ---------------------------------------------------------------------------
// Kernel B: LDS-free bf16 MFMA GEMM + fused BCE loss. 1024 blocks, 32x32
// tile each (4 blocks/CU -> 16 waves/CU latency hiding). Wave w of 4 owns
// the 16x16 quadrant (wr=w>>1, wc=w&1). A/B fragments load straight from
// L2-resident Ab/Bb; img-row inverse norms computed from the in-register A
// fragments (shfl-combine quarters + shfl broadcast -- no LDS, no barrier).
// Loss: wave reduce -> LDS red[4] -> one atomicAdd into a 64B-strided
// partial (<=64 same-address RMWs) -> ticket winner sums 16 partials with a
// single 16-lane acquire-load round trip.
// ---------------------------------------------------------------------------
__global__ __launch_bounds__(256) void gemm_loss_kernel(const unsigned short* __restrict__ Ab,
                                                        const unsigned short* __restrict__ Bb,
                                                        const int* __restrict__ labels,
                                                        Ctrl* __restrict__ ctrl,
                                                        float* __restrict__ out) {
    __shared__ float red[4];

    const int t    = threadIdx.x;
    const int w    = t >> 6;
    const int lane = t & 63;
    const int m16  = lane & 15;
    const int kg   = lane >> 4;
    const int wr   = w >> 1;
    const int wc   = w & 1;

    const int rowBase = (blockIdx.x & 31) << 5;    // A rows (img)
    const int colBase = (blockIdx.x >> 5) << 5;    // B rows (text) = logit cols

    // Fragment loads (all issued up front; 16 outstanding loads/lane).
    const unsigned short* arow = Ab + (size_t)(rowBase + (wr << 4) + m16) * C_N;
    const unsigned short* brow = Bb + (size_t)(colBase + (wc << 4) + m16) * C_N;
    bf16x8 aF[8], bF[8];
    #pragma unroll
    for (int s = 0; s < 8; ++s) {
        const int koff = ((s << 2) + kg) << 3;     // 16B chunk: kc = s*4+kg
        aF[s] = *(const bf16x8*)(arow + koff);
        bF[s] = *(const bf16x8*)(brow + koff);
    }

    // Deferred normalization: lane holds the kg-quarter of img row
    // (rowBase + wr*16 + m16). Combine quarters, then shfl-broadcast the
    // inverse norms of rows kg*4+r (the rows this lane's acc regs map to).
    float ss = 0.0f;
    #pragma unroll
    for (int s = 0; s < 8; ++s) {
        #pragma unroll
        for (int e = 0; e < 8; ++e) {
            const float f = bf2f((unsigned short)aF[s][e]);
            ss += f * f;
        }
    }
    ss += __shfl_xor(ss, 16, 64);
    ss += __shfl_xor(ss, 32, 64);
    const float inv = 1.0f / fmaxf(sqrtf(ss), 1e-12f);   // lane: row m16 of quadrant

    f32x4 acc = {0.f, 0.f, 0.f, 0.f};
    #pragma unroll
    for (int s = 0; s < 8; ++s)
        acc = __builtin_amdgcn_mfma_f32_16x16x32_bf16(aF[s], bF[s], acc, 0, 0, 0);

    // Epilogue. D frag: col = lane&15, row = (lane>>4)*4 + reg [m89/m91].
    float lsum = 0.0f;
    const int gj   = colBase + (wc << 4) + m16;
    const int labj = labels[gj];
    #pragma unroll
    for (int r = 0; r < 4; ++r) {
        const int lrow = (kg << 2) + r;            // row within quadrant
        const float sA = __shfl(inv, lrow, 64) * TEMP_INV;   // lanes 0..15 hold rows 0..15
        const int   gi = rowBase + (wr << 4) + lrow;
        const float x  = acc[r] * sA;
        const float z  = (labels[gi] == labj) ? 1.0f : 0.0f;
        const float sp = fmaxf(x, 0.0f) + __logf(1.0f + __expf(-fabsf(x)));
        lsum += sp - x * z;
    }
    #pragma unroll
    for (int off = 32; off > 0; off >>= 1) lsum += __shfl_xor(lsum, off, 64);
    if (lane == 0) red[w] = lsum;
    __syncthreads();

    if (w == 0) {
        const float bsum = red[0] + red[1] + red[2] + red[3];
        unsigned old = 0u;
        if (lane == 0) {
            atomicAdd(&ctrl->part[(blockIdx.x & 15) << 4], bsum);
            __threadfence();
            old = atomicAdd(&ctrl->ticket, 1u);
        }
        old = __shfl(old, 0, 64);
        if (old == (unsigned)(GEMM_BLOCKS - 1)) {  // last block: finalize
            float v = 0.0f;
            if (lane < 16)
                v = __hip_atomic_load(&ctrl->part[lane << 4], __ATOMIC_ACQUIRE,
                                      __HIP_MEMORY_SCOPE_AGENT);
            #pragma unroll
            for (int off = 8; off > 0; off >>= 1) v += __shfl_xor(v, off, 64);
            if (lane == 0)
                out[0] = v * (1.0f / ((float)B_N * (float)B_N));
        }
    }
}

extern "C" void kernel_launch(void* const* d_in, const int* in_sizes, int n_in,
                              void* d_out, int out_size, void* d_ws, size_t ws_size,
                              hipStream_t stream) {
    const float* img    = (const float*)d_in[0];   // [1024,256,24,24] fp32
    const float* text   = (const float*)d_in[1];   // [1024,256] fp32
    const int*   labels = (const int*)d_in[2];     // [1024] int32 (JAX demotes int64)
    float* out = (float*)d_out;

    char* ws = (char*)d_ws;
    unsigned short* Ab   = (unsigned short*)ws;                 // 512 KiB bf16 (unnormalized means)
    unsigned short* Bb   = (unsigned short*)(ws + (512 << 10)); // 512 KiB bf16 (normalized text)
    Ctrl*           ctrl = (Ctrl*)(ws + (1 << 20));             // ~1 KiB control

    pool_kernel<<<32 + 16384, 256, 0, stream>>>(img, text, Ab, Bb, ctrl);
    gemm_loss_kernel<<<GEMM_BLOCKS, 256, 0, stream>>>(Ab, Bb, labels, ctrl, out);
}

// Round 8
// 116.735 us; speedup vs baseline: 24.1631x; 1.1309x over previous
//
#include <hip/hip_runtime.h>
#include <math.h>

// Problem constants (from reference): B=1024, C=256, H=W=24
static constexpr int B_N  = 1024;
static constexpr int C_N  = 256;
static constexpr int HW_N = 576;           // floats per channel = 144 float4
static constexpr float TEMP_INV = 1.0f / 0.07f;

static constexpr int GEMM_BLOCKS = 1024;   // 32x32 tiles of the 1024x1024 logits

typedef __attribute__((ext_vector_type(8))) short bf16x8;
typedef __attribute__((ext_vector_type(4))) float f32x4;
typedef __attribute__((ext_vector_type(4))) float f4v;

// Control block in ws. part[i*16] (64B-strided, no false sharing) hold loss
// partials; ticket elects the finalizing block. Zeroed by pool block 0 (runs
// one launch earlier -> safe on every graph replay).
struct Ctrl {
    float    part[16 * 16];
    unsigned ticket;
};

// float -> bf16 round-to-nearest-even (inputs finite)
static __device__ __forceinline__ unsigned short f2bf(float f) {
    unsigned u = __float_as_uint(f);
    return (unsigned short)((u + 0x7FFFu + ((u >> 16) & 1u)) >> 16);
}
static __device__ __forceinline__ float bf2f(unsigned short h) {
    return __uint_as_float(((unsigned)h) << 16);
}

// ---------------------------------------------------------------------------
// Kernel A (byte-identical logic to R5's proven pool): pool + text normalize.
//  Blocks 0..31    : text rows (32/block): fp32 L2-normalize + bf16 -> Bb.
//                    Block 0 also zeroes the Ctrl partials + ticket.
//  Blocks 32..16415: pooling. Each wave owns 4 channels = 576 float4.
//                    9 dense NONTEMPORAL loads/lane issued before any use
//                    (deep vmcnt pipe), select-accumulate into 4 channel
//                    partials, 4 interleaved butterflies, lane 0 writes the
//                    4 UNNORMALIZED means as bf16 to Ab (normalization
//                    deferred to the GEMM).
// ---------------------------------------------------------------------------
__global__ __launch_bounds__(256) void pool_kernel(const float* __restrict__ img,
                                                   const float* __restrict__ text,
                                                   unsigned short* __restrict__ Ab,
                                                   unsigned short* __restrict__ Bb,
                                                   Ctrl* __restrict__ ctrl) {
    const int t    = threadIdx.x;
    const int w    = t >> 6;
    const int lane = t & 63;

    if (blockIdx.x < 32) {
        if (blockIdx.x == 0 && t < 17) {
            if (t < 16) ctrl->part[t * 16] = 0.0f;
            else        ctrl->ticket = 0u;
        }
        const int r0 = blockIdx.x * 32 + w * 8;
        #pragma unroll
        for (int rr = 0; rr < 8; ++rr) {
            const int r = r0 + rr;
            const f4v v = ((const f4v*)(text + (size_t)r * C_N))[lane];
            float ss = v.x * v.x + v.y * v.y + v.z * v.z + v.w * v.w;
            #pragma unroll
            for (int off = 32; off > 0; off >>= 1) ss += __shfl_xor(ss, off, 64);
            const float inv = 1.0f / fmaxf(sqrtf(ss), 1e-12f);   // matches F.normalize
            ushort4 o;
            o.x = f2bf(v.x * inv); o.y = f2bf(v.y * inv);
            o.z = f2bf(v.z * inv); o.w = f2bf(v.w * inv);
            ((ushort4*)(Bb + (size_t)r * C_N))[lane] = o;
        }
        return;
    }

    const int g = blockIdx.x - 32;                 // 0..16383, 16 channels each
    const size_t ch4 = (size_t)g * 16 + (size_t)w * 4;
    const f4v* src = (const f4v*)img + ch4 * 144;

    // Issue all 9 loads before any use (independent dests -> deep vmcnt pipe).
    f4v vv[9];
    #pragma unroll
    for (int j = 0; j < 9; ++j)
        vv[j] = __builtin_nontemporal_load(&src[j * 64 + lane]);

    float a0 = 0.f, a1 = 0.f, a2 = 0.f, a3 = 0.f;
    #pragma unroll
    for (int j = 0; j < 9; ++j) {
        const int idx = j * 64 + lane;             // f4 index in [0, 576)
        const float s = (vv[j].x + vv[j].y) + (vv[j].z + vv[j].w);
        // channel boundaries at 144/288/432; 6 of 9 j's fold at compile time
        a0 += (idx < 144)               ? s : 0.0f;
        a1 += (idx >= 144 && idx < 288) ? s : 0.0f;
        a2 += (idx >= 288 && idx < 432) ? s : 0.0f;
        a3 += (idx >= 432)              ? s : 0.0f;
    }

    // 4 interleaved butterflies: independent chains hide bpermute latency.
    #pragma unroll
    for (int off = 32; off > 0; off >>= 1) {
        a0 += __shfl_xor(a0, off, 64);
        a1 += __shfl_xor(a1, off, 64);
        a2 += __shfl_xor(a2, off, 64);
        a3 += __shfl_xor(a3, off, 64);
    }
    if (lane == 0) {
        const float sc = 1.0f / (float)HW_N;
        ushort4 o;
        o.x = f2bf(a0 * sc); o.y = f2bf(a1 * sc);
        o.z = f2bf(a2 * sc); o.w = f2bf(a3 * sc);
        ((ushort4*)Ab)[ch4 >> 2] = o;              // unnormalized means
    }
}

// ---------------------------------------------------------------------------
// Kernel B: bf16 MFMA GEMM, R5 structure with 32x32 tiles x 1024 blocks
// (32 KB LDS/block -> 4 blocks/CU, 16 waves/CU vs R5's 8). Whole K=256
// staged once, XOR-swizzled, coalesced global loads. In-kernel deferred
// img-row norms from staged LDS. Fused BCE loss; 16 padded partials +
// ticket finalize (R7-proven).
// Wave w owns quadrant (wr=w>>1, wc=w&1) = rows wr*16..+16 x cols wc*16..+16.
// ---------------------------------------------------------------------------
__global__ __launch_bounds__(256) void gemm_loss_kernel(const unsigned short* __restrict__ Ab,
                                                        const unsigned short* __restrict__ Bb,
                                                        const int* __restrict__ labels,
                                                        Ctrl* __restrict__ ctrl,
                                                        float* __restrict__ out) {
    __shared__ unsigned short Abuf[32 * 256];   // 16 KB, swizzled
    __shared__ unsigned short Bbuf[32 * 256];   // 16 KB, swizzled
    __shared__ float invA[32];
    __shared__ float red[4];

    const int t = threadIdx.x;
    const int rowBase = (blockIdx.x & 31) << 5;
    const int colBase = (blockIdx.x >> 5) << 5;

    // ---- Stage both 32x256 bf16 tiles. 1024 16B-chunks each, 4 per thread:
    // chunk c -> (row = c>>5, kc = c&31); LDS byte = (row*512+kc*16) ^ ((row&7)<<4).
    #pragma unroll
    for (int i = 0; i < 4; ++i) {
        const int c   = t + (i << 8);           // 0..1023
        const int row = c >> 5;
        const int kc  = c & 31;
        const unsigned off = (unsigned)((row << 9) + (kc << 4)) ^ (unsigned)((row & 7) << 4);
        uint4 va = ((const uint4*)(Ab + (size_t)(rowBase + row) * C_N))[kc];
        *(uint4*)((char*)Abuf + off) = va;
        uint4 vb = ((const uint4*)(Bb + (size_t)(colBase + row) * C_N))[kc];
        *(uint4*)((char*)Bbuf + off) = vb;
    }
    __syncthreads();

    // ---- Deferred normalization: inverse L2 norms of the 32 staged img rows.
    // Thread t -> row t>>3, eighth q = t&7 (4 chunks each).
    {
        const int row = t >> 3;
        const int q   = t & 7;
        float ss = 0.0f;
        #pragma unroll
        for (int j = 0; j < 4; ++j) {
            const int kc = (q << 2) + j;
            const unsigned off = (unsigned)((row << 9) + (kc << 4)) ^ (unsigned)((row & 7) << 4);
            const bf16x8 v = *(const bf16x8*)((char*)Abuf + off);
            #pragma unroll
            for (int e = 0; e < 8; ++e) {
                const float f = bf2f((unsigned short)v[e]);
                ss += f * f;
            }
        }
        ss += __shfl_xor(ss, 1, 64);              // combine the 8 eighth-rows
        ss += __shfl_xor(ss, 2, 64);
        ss += __shfl_xor(ss, 4, 64);
        if (q == 0) invA[row] = 1.0f / fmaxf(sqrtf(ss), 1e-12f);
    }
    __syncthreads();

    // ---- MFMA: one 16x16 quadrant per wave, K = 256 = 8 chunks of 32.
    const int w    = t >> 6;
    const int lane = t & 63;
    const int m16  = lane & 15;
    const int kg   = lane >> 4;
    const int wr   = w >> 1;
    const int wc   = w & 1;

    f32x4 acc = {0.f, 0.f, 0.f, 0.f};
    #pragma unroll
    for (int s = 0; s < 8; ++s) {
        const int kc   = (s << 2) + kg;
        const int arow = (wr << 4) + m16;
        const int brow = (wc << 4) + m16;
        const bf16x8 a = *(const bf16x8*)((char*)Abuf +
                            (((unsigned)((arow << 9) + (kc << 4))) ^ (unsigned)((arow & 7) << 4)));
        const bf16x8 b = *(const bf16x8*)((char*)Bbuf +
                            (((unsigned)((brow << 9) + (kc << 4))) ^ (unsigned)((brow & 7) << 4)));
        acc = __builtin_amdgcn_mfma_f32_16x16x32_bf16(a, b, acc, 0, 0, 0);
    }

    // ---- Epilogue. D frag: col = lane&15, row = (lane>>4)*4 + reg [m89/m91].
    float lsum = 0.0f;
    const int lr0  = (wr << 4) + (kg << 2);       // tile-local row of acc reg 0
    const int gj   = colBase + (wc << 4) + m16;
    const int labj = labels[gj];
    #pragma unroll
    for (int r = 0; r < 4; ++r) {
        const float sA = invA[lr0 + r] * TEMP_INV;
        const float x  = acc[r] * sA;
        const float z  = (labels[rowBase + lr0 + r] == labj) ? 1.0f : 0.0f;
        const float sp = fmaxf(x, 0.0f) + __logf(1.0f + __expf(-fabsf(x)));
        lsum += sp - x * z;
    }
    #pragma unroll
    for (int off = 32; off > 0; off >>= 1) lsum += __shfl_xor(lsum, off, 64);
    if (lane == 0) red[w] = lsum;
    __syncthreads();

    if (w == 0) {
        const float bsum = red[0] + red[1] + red[2] + red[3];
        unsigned old = 0u;
        if (lane == 0) {
            atomicAdd(&ctrl->part[(blockIdx.x & 15) << 4], bsum);
            __threadfence();
            old = atomicAdd(&ctrl->ticket, 1u);
        }
        old = __shfl(old, 0, 64);
        if (old == (unsigned)(GEMM_BLOCKS - 1)) {  // last block: finalize
            float v = 0.0f;
            if (lane < 16)
                v = __hip_atomic_load(&ctrl->part[lane << 4], __ATOMIC_ACQUIRE,
                                      __HIP_MEMORY_SCOPE_AGENT);
            #pragma unroll
            for (int off = 8; off > 0; off >>= 1) v += __shfl_xor(v, off, 64);
            if (lane == 0)
                out[0] = v * (1.0f / ((float)B_N * (float)B_N));
        }
    }
}

extern "C" void kernel_launch(void* const* d_in, const int* in_sizes, int n_in,
                              void* d_out, int out_size, void* d_ws, size_t ws_size,
                              hipStream_t stream) {
    const float* img    = (const float*)d_in[0];   // [1024,256,24,24] fp32
    const float* text   = (const float*)d_in[1];   // [1024,256] fp32
    const int*   labels = (const int*)d_in[2];     // [1024] int32 (JAX demotes int64)
    float* out = (float*)d_out;

    char* ws = (char*)d_ws;
    unsigned short* Ab   = (unsigned short*)ws;                 // 512 KiB bf16 (unnormalized means)
    unsigned short* Bb   = (unsigned short*)(ws + (512 << 10)); // 512 KiB bf16 (normalized text)
    Ctrl*           ctrl = (Ctrl*)(ws + (1 << 20));             // ~1 KiB control

    pool_kernel<<<32 + 16384, 256, 0, stream>>>(img, text, Ab, Bb, ctrl);
    gemm_loss_kernel<<<GEMM_BLOCKS, 256, 0, stream>>>(Ab, Bb, labels, ctrl, out);
}

// Round 9
// 104.071 us; speedup vs baseline: 27.1035x; 1.1217x over previous
//
#include <hip/hip_runtime.h>
#include <math.h>

// Problem constants (from reference): B=1024, C=256, H=W=24
static constexpr int B_N  = 1024;
static constexpr int C_N  = 256;
static constexpr int HW_N = 576;           // floats per channel = 144 float4
static constexpr float TEMP_INV = 1.0f / 0.07f;

static constexpr int GEMM_BLOCKS = 256;    // 64x64 tiles of the 1024x1024 logits

typedef __attribute__((ext_vector_type(8))) short bf16x8;
typedef __attribute__((ext_vector_type(4))) float f32x4;
typedef __attribute__((ext_vector_type(4))) float f4v;

// Control block in ws. part[i*16] (64B-strided, no false sharing) hold loss
// partials; ticket elects the finalizing block. Zeroed by pool block 0 (runs
// one launch earlier -> safe on every graph replay).
struct Ctrl {
    float    part[16 * 16];
    unsigned ticket;
};

// float -> bf16 round-to-nearest-even (inputs finite)
static __device__ __forceinline__ unsigned short f2bf(float f) {
    unsigned u = __float_as_uint(f);
    return (unsigned short)((u + 0x7FFFu + ((u >> 16) & 1u)) >> 16);
}
static __device__ __forceinline__ float bf2f(unsigned short h) {
    return __uint_as_float(((unsigned)h) << 16);
}

// ---------------------------------------------------------------------------
// Kernel A (R5-proven, unchanged): pool + concurrent text normalize.
//  Blocks 0..31    : text rows (32/block): fp32 L2-normalize + bf16 -> Bb.
//                    Block 0 also zeroes the Ctrl partials + ticket.
//  Blocks 32..16415: pooling. Each wave owns 4 channels = 576 float4.
//                    9 dense NONTEMPORAL loads/lane issued before any use
//                    (deep vmcnt pipe), select-accumulate into 4 channel
//                    partials, 4 interleaved butterflies, lane 0 writes the
//                    4 UNNORMALIZED means as bf16 to Ab (normalization
//                    deferred to the GEMM).
// ---------------------------------------------------------------------------
__global__ __launch_bounds__(256) void pool_kernel(const float* __restrict__ img,
                                                   const float* __restrict__ text,
                                                   unsigned short* __restrict__ Ab,
                                                   unsigned short* __restrict__ Bb,
                                                   Ctrl* __restrict__ ctrl) {
    const int t    = threadIdx.x;
    const int w    = t >> 6;
    const int lane = t & 63;

    if (blockIdx.x < 32) {
        if (blockIdx.x == 0 && t < 17) {
            if (t < 16) ctrl->part[t * 16] = 0.0f;
            else        ctrl->ticket = 0u;
        }
        const int r0 = blockIdx.x * 32 + w * 8;
        #pragma unroll
        for (int rr = 0; rr < 8; ++rr) {
            const int r = r0 + rr;
            const f4v v = ((const f4v*)(text + (size_t)r * C_N))[lane];
            float ss = v.x * v.x + v.y * v.y + v.z * v.z + v.w * v.w;
            #pragma unroll
            for (int off = 32; off > 0; off >>= 1) ss += __shfl_xor(ss, off, 64);
            const float inv = 1.0f / fmaxf(sqrtf(ss), 1e-12f);   // matches F.normalize
            ushort4 o;
            o.x = f2bf(v.x * inv); o.y = f2bf(v.y * inv);
            o.z = f2bf(v.z * inv); o.w = f2bf(v.w * inv);
            ((ushort4*)(Bb + (size_t)r * C_N))[lane] = o;
        }
        return;
    }

    const int g = blockIdx.x - 32;                 // 0..16383, 16 channels each
    const size_t ch4 = (size_t)g * 16 + (size_t)w * 4;
    const f4v* src = (const f4v*)img + ch4 * 144;

    // Issue all 9 loads before any use (independent dests -> deep vmcnt pipe).
    f4v vv[9];
    #pragma unroll
    for (int j = 0; j < 9; ++j)
        vv[j] = __builtin_nontemporal_load(&src[j * 64 + lane]);

    float a0 = 0.f, a1 = 0.f, a2 = 0.f, a3 = 0.f;
    #pragma unroll
    for (int j = 0; j < 9; ++j) {
        const int idx = j * 64 + lane;             // f4 index in [0, 576)
        const float s = (vv[j].x + vv[j].y) + (vv[j].z + vv[j].w);
        // channel boundaries at 144/288/432; 6 of 9 j's fold at compile time
        a0 += (idx < 144)               ? s : 0.0f;
        a1 += (idx >= 144 && idx < 288) ? s : 0.0f;
        a2 += (idx >= 288 && idx < 432) ? s : 0.0f;
        a3 += (idx >= 432)              ? s : 0.0f;
    }

    // 4 interleaved butterflies: independent chains hide bpermute latency.
    #pragma unroll
    for (int off = 32; off > 0; off >>= 1) {
        a0 += __shfl_xor(a0, off, 64);
        a1 += __shfl_xor(a1, off, 64);
        a2 += __shfl_xor(a2, off, 64);
        a3 += __shfl_xor(a3, off, 64);
    }
    if (lane == 0) {
        const float sc = 1.0f / (float)HW_N;
        ushort4 o;
        o.x = f2bf(a0 * sc); o.y = f2bf(a1 * sc);
        o.z = f2bf(a2 * sc); o.w = f2bf(a3 * sc);
        ((ushort4*)Ab)[ch4 >> 2] = o;              // unnormalized means
    }
}

// ---------------------------------------------------------------------------
// Kernel B: bf16 MFMA GEMM, R5 geometry (64x64 tile, 256 blocks, whole K=256
// staged once, XOR-swizzled) but with 512 THREADS (8 waves) per block: same
// total staging traffic (16 MB), 2x the latency overlap at 1 block/CU.
// Wave w (0..7) owns frag-row fr=w>>1 (16 rows) x col-frags {cb, cb+1} where
// cb = (w&1)*2 -- two 16x16 MFMA fragments per wave.
// In-kernel deferred img-row norms; fused BCE loss; 16 padded partials +
// ticket finalize (R7/R8-proven).
// ---------------------------------------------------------------------------
__global__ __launch_bounds__(512) void gemm_loss_kernel(const unsigned short* __restrict__ Ab,
                                                        const unsigned short* __restrict__ Bb,
                                                        const int* __restrict__ labels,
                                                        Ctrl* __restrict__ ctrl,
                                                        float* __restrict__ out) {
    __shared__ unsigned short Abuf[64 * 256];   // 32 KB, swizzled
    __shared__ unsigned short Bbuf[64 * 256];   // 32 KB, swizzled
    __shared__ float invA[64];
    __shared__ float red[8];

    const int t = threadIdx.x;
    const int rowBase = (blockIdx.x & 15) << 6;
    const int colBase = (blockIdx.x >> 4) << 6;

    // ---- Stage both 64x256 bf16 tiles. 2048 16B-chunks each, 4 per thread:
    // chunk c -> (row = c>>5, kc = c&31); LDS byte = (row*512+kc*16) ^ ((row&7)<<4).
    #pragma unroll
    for (int i = 0; i < 4; ++i) {
        const int c   = t + (i << 9);           // 0..2047
        const int row = c >> 5;
        const int kc  = c & 31;
        const unsigned off = (unsigned)((row << 9) + (kc << 4)) ^ (unsigned)((row & 7) << 4);
        uint4 va = ((const uint4*)(Ab + (size_t)(rowBase + row) * C_N))[kc];
        *(uint4*)((char*)Abuf + off) = va;
        uint4 vb = ((const uint4*)(Bb + (size_t)(colBase + row) * C_N))[kc];
        *(uint4*)((char*)Bbuf + off) = vb;
    }
    __syncthreads();

    // ---- Deferred normalization: inverse L2 norms of the 64 staged img rows.
    // Thread t -> row t>>3, eighth q = t&7 (4 chunks each).
    {
        const int row = t >> 3;
        const int q   = t & 7;
        float ss = 0.0f;
        #pragma unroll
        for (int j = 0; j < 4; ++j) {
            const int kc = (q << 2) + j;
            const unsigned off = (unsigned)((row << 9) + (kc << 4)) ^ (unsigned)((row & 7) << 4);
            const bf16x8 v = *(const bf16x8*)((char*)Abuf + off);
            #pragma unroll
            for (int e = 0; e < 8; ++e) {
                const float f = bf2f((unsigned short)v[e]);
                ss += f * f;
            }
        }
        ss += __shfl_xor(ss, 1, 64);              // combine the 8 eighth-rows
        ss += __shfl_xor(ss, 2, 64);
        ss += __shfl_xor(ss, 4, 64);
        if (q == 0) invA[row] = 1.0f / fmaxf(sqrtf(ss), 1e-12f);
    }
    __syncthreads();

    // ---- MFMA: wave w -> frag-row fr (16 rows), col-frags cb..cb+1.
    const int w    = t >> 6;                      // 0..7
    const int lane = t & 63;
    const int m16  = lane & 15;
    const int kg   = lane >> 4;
    const int fr   = w >> 1;                      // 0..3
    const int cb   = (w & 1) << 1;                // 0 or 2

    f32x4 acc[2] = {{0.f, 0.f, 0.f, 0.f}, {0.f, 0.f, 0.f, 0.f}};
    #pragma unroll
    for (int s = 0; s < 8; ++s) {                 // K = 256 = 8 * 32
        const int kc   = (s << 2) + kg;
        const int arow = (fr << 4) + m16;
        const bf16x8 a = *(const bf16x8*)((char*)Abuf +
                            (((unsigned)((arow << 9) + (kc << 4))) ^ (unsigned)((arow & 7) << 4)));
        #pragma unroll
        for (int ct = 0; ct < 2; ++ct) {
            const int brow = ((cb + ct) << 4) + m16;
            const bf16x8 b = *(const bf16x8*)((char*)Bbuf +
                                (((unsigned)((brow << 9) + (kc << 4))) ^ (unsigned)((brow & 7) << 4)));
            acc[ct] = __builtin_amdgcn_mfma_f32_16x16x32_bf16(a, b, acc[ct], 0, 0, 0);
        }
    }

    // ---- Epilogue. D frag: col = lane&15, row = (lane>>4)*4 + reg [m89/m91].
    float lsum = 0.0f;
    const int lr0 = (fr << 4) + (kg << 2);        // tile-local row of acc reg 0
    #pragma unroll
    for (int ct = 0; ct < 2; ++ct) {
        const int gj   = colBase + ((cb + ct) << 4) + m16;
        const int labj = labels[gj];
        #pragma unroll
        for (int r = 0; r < 4; ++r) {
            const float sA = invA[lr0 + r] * TEMP_INV;
            const float x  = acc[ct][r] * sA;
            const float z  = (labels[rowBase + lr0 + r] == labj) ? 1.0f : 0.0f;
            const float sp = fmaxf(x, 0.0f) + __logf(1.0f + __expf(-fabsf(x)));
            lsum += sp - x * z;
        }
    }
    #pragma unroll
    for (int off = 32; off > 0; off >>= 1) lsum += __shfl_xor(lsum, off, 64);
    if (lane == 0) red[w] = lsum;
    __syncthreads();

    if (w == 0) {
        const float bsum = (red[0] + red[1]) + (red[2] + red[3])
                         + (red[4] + red[5]) + (red[6] + red[7]);
        unsigned old = 0u;
        if (lane == 0) {
            atomicAdd(&ctrl->part[(blockIdx.x & 15) << 4], bsum);
            __threadfence();
            old = atomicAdd(&ctrl->ticket, 1u);
        }
        old = __shfl(old, 0, 64);
        if (old == (unsigned)(GEMM_BLOCKS - 1)) {  // last block: finalize
            float v = 0.0f;
            if (lane < 16)
                v = __hip_atomic_load(&ctrl->part[lane << 4], __ATOMIC_ACQUIRE,
                                      __HIP_MEMORY_SCOPE_AGENT);
            #pragma unroll
            for (int off = 8; off > 0; off >>= 1) v += __shfl_xor(v, off, 64);
            if (lane == 0)
                out[0] = v * (1.0f / ((float)B_N * (float)B_N));
        }
    }
}

extern "C" void kernel_launch(void* const* d_in, const int* in_sizes, int n_in,
                              void* d_out, int out_size, void* d_ws, size_t ws_size,
                              hipStream_t stream) {
    const float* img    = (const float*)d_in[0];   // [1024,256,24,24] fp32
    const float* text   = (const float*)d_in[1];   // [1024,256] fp32
    const int*   labels = (const int*)d_in[2];     // [1024] int32 (JAX demotes int64)
    float* out = (float*)d_out;

    char* ws = (char*)d_ws;
    unsigned short* Ab   = (unsigned short*)ws;                 // 512 KiB bf16 (unnormalized means)
    unsigned short* Bb   = (unsigned short*)(ws + (512 << 10)); // 512 KiB bf16 (normalized text)
    Ctrl*           ctrl = (Ctrl*)(ws + (1 << 20));             // ~1 KiB control

    pool_kernel<<<32 + 16384, 256, 0, stream>>>(img, text, Ab, Bb, ctrl);
    gemm_loss_kernel<<<GEMM_BLOCKS, 512, 0, stream>>>(Ab, Bb, labels, ctrl, out);
}